// Round 13
// baseline (702.587 us; speedup 1.0000x reference)
//
#include <hip/hip_runtime.h>
#include <hip/hip_bf16.h>
#include <math.h>

#define NGRAPHS 256
#define BSHIFT 7
#define NBUCK 1024   // 128-node buckets; covers N up to 131072
#define NSORT 128    // blocks for bhist/bscatter (256 threads each) — measured sweet spot
#define SMASK 0x01FFFFFFu  // low 25 bits = src (N < 2^25)

// ---------------- bucket histogram: per-block LDS hist -> dense matrix (no global atomics) ----------------
__global__ __launch_bounds__(256) void k_bhist(const int* __restrict__ dst, int* __restrict__ hmat, int E) {
    __shared__ int hist[NBUCK];
    for (int i = threadIdx.x; i < NBUCK; i += 256) hist[i] = 0;
    __syncthreads();
    int chunk = (E + NSORT - 1) / NSORT;
    int lo = blockIdx.x * chunk;
    int hi = lo + chunk; if (hi > E) hi = E;
    for (int i = lo + threadIdx.x; i < hi; i += 256) {
        int d = __builtin_nontemporal_load(dst + i);
        atomicAdd(&hist[d >> BSHIFT], 1);
    }
    __syncthreads();
    for (int i = threadIdx.x; i < NBUCK; i += 256)
        hmat[(size_t)blockIdx.x * NBUCK + i] = hist[i];  // coalesced dump
}

// ---------------- column scan: per-bucket exclusive prefix over the NSORT block rows ----------------
__global__ __launch_bounds__(256) void k_cscan(int* __restrict__ hmat, int* __restrict__ btot) {
    int col = blockIdx.x * 256 + threadIdx.x;  // one thread per bucket
    int run = 0;
#pragma unroll 4
    for (int r = 0; r < NSORT; r++) {
        int v = hmat[(size_t)r * NBUCK + col];   // coalesced across threads
        hmat[(size_t)r * NBUCK + col] = run;
        run += v;
    }
    btot[col] = run;
}

// ---------------- bucket scan: one block, 1024 threads -> global bucket offsets ----------------
__global__ __launch_bounds__(1024) void k_bscan(const int* __restrict__ btot, int* __restrict__ bstart) {
    __shared__ int s[1024];
    int tid = threadIdx.x;
    int v = btot[tid];
    s[tid] = v;
    __syncthreads();
    for (int off = 1; off < 1024; off <<= 1) {
        int t = (tid >= off) ? s[tid - off] : 0;
        __syncthreads();
        s[tid] += t;
        __syncthreads();
    }
    bstart[tid] = s[tid] - v;  // exclusive
    if (tid == 1023) bstart[NBUCK] = s[1023];
}

// ---------------- scatter into bucket-ordered ebuf via precomputed LDS cursors ----------------
// pack: word = src | (dst&127)<<25
__global__ __launch_bounds__(256) void k_bscatter(const int* __restrict__ src, const int* __restrict__ dst,
                                                  const int* __restrict__ hmat, const int* __restrict__ bstart,
                                                  unsigned* __restrict__ ebuf, int E) {
    __shared__ int cur[NBUCK];
    for (int i = threadIdx.x; i < NBUCK; i += 256)
        cur[i] = bstart[i] + hmat[(size_t)blockIdx.x * NBUCK + i];
    __syncthreads();
    int chunk = (E + NSORT - 1) / NSORT;
    int lo = blockIdx.x * chunk;
    int hi = lo + chunk; if (hi > E) hi = E;
    for (int i = lo + threadIdx.x; i < hi; i += 256) {
        int d = __builtin_nontemporal_load(dst + i);
        int s = __builtin_nontemporal_load(src + i);
        int p = atomicAdd(&cur[d >> BSHIFT], 1);
        ebuf[p] = (unsigned)s | ((unsigned)(d & 127) << 25);
    }
}

// ---------------- per-bucket LDS counting sort (128 nodes) -> full CSR + row_start ----------------
__global__ __launch_bounds__(256) void k_sort2(const unsigned* __restrict__ ebuf, const int* __restrict__ bstart,
                                               int* __restrict__ csr, int* __restrict__ row_start, int N) {
    __shared__ int hist[128];
    __shared__ int sc[128];
    __shared__ int scur[128];
    int b = blockIdx.x;
    int e0 = bstart[b], e1 = bstart[b + 1];
    if (threadIdx.x < 128) hist[threadIdx.x] = 0;
    __syncthreads();
    for (int i = e0 + threadIdx.x; i < e1; i += 256)
        atomicAdd(&hist[__builtin_nontemporal_load(ebuf + i) >> 25], 1);
    __syncthreads();
    // Hillis-Steele inclusive scan over 128 entries
    if (threadIdx.x < 128) sc[threadIdx.x] = hist[threadIdx.x];
    __syncthreads();
    for (int off = 1; off < 128; off <<= 1) {
        int t = 0;
        if (threadIdx.x < 128 && threadIdx.x >= off) t = sc[threadIdx.x - off];
        __syncthreads();
        if (threadIdx.x < 128) sc[threadIdx.x] += t;
        __syncthreads();
    }
    if (threadIdx.x < 128) {
        int inc = sc[threadIdx.x];
        int ex = inc - hist[threadIdx.x];
        scur[threadIdx.x] = e0 + ex;
        int node = (b << BSHIFT) + threadIdx.x;
        if (node < N) row_start[node] = e0 + ex;
        if (node == N - 1) row_start[N] = e0 + inc;  // == E
    }
    __syncthreads();
    for (int i = e0 + threadIdx.x; i < e1; i += 256) {
        unsigned w = __builtin_nontemporal_load(ebuf + i);
        int p = atomicAdd(&scur[w >> 25], 1);
        csr[p] = (int)(w & SMASK);
    }
}

// ---------------- generic dense layer, one thread per (node, channel-quad), optional fused BN partials ----------------
template <int CI, int CO, bool HAS_REL, bool HAS_ROOT, bool ADD_AGG, bool HAS_BIAS, bool STATS>
__global__ __launch_bounds__(256) void k_lin(const float* __restrict__ hroot, const float* __restrict__ hrel,
                                             const float* __restrict__ w_rel, const float* __restrict__ w_root,
                                             const float* __restrict__ bias, const float* __restrict__ aggadd,
                                             float* __restrict__ out, float* __restrict__ partials, int N) {
    constexpr int QPR = CO / 4;
    __shared__ float s_rel[HAS_REL ? CI * CO : 1];
    __shared__ float s_root[HAS_ROOT ? CI * CO : 1];
    __shared__ float s_b[HAS_BIAS ? CO : 4];
    if (HAS_REL)
        for (int i = threadIdx.x; i < CI * CO; i += 256) s_rel[i] = w_rel[i];
    if (HAS_ROOT)
        for (int i = threadIdx.x; i < CI * CO; i += 256) s_root[i] = w_root[i];
    if (HAS_BIAS && threadIdx.x < CO) s_b[threadIdx.x] = bias[threadIdx.x];
    __syncthreads();

    int t = blockIdx.x * 256 + threadIdx.x;
    int n = t / QPR;
    int c0 = (t % QPR) * 4;
    bool valid = n < N;
    int nn = valid ? n : 0;

    float rr[HAS_ROOT ? CI : 1];
    if (HAS_ROOT) {
        const float4* hp = (const float4*)(hroot + (size_t)nn * CI);
#pragma unroll
        for (int i = 0; i < CI / 4; i++) {
            float4 v = hp[i];
            rr[4 * i + 0] = v.x; rr[4 * i + 1] = v.y; rr[4 * i + 2] = v.z; rr[4 * i + 3] = v.w;
        }
    }
    float ar[HAS_REL ? CI : 1];
    if (HAS_REL) {
        const float4* mp = (const float4*)(hrel + (size_t)nn * CI);
#pragma unroll
        for (int i = 0; i < CI / 4; i++) {
            float4 v = mp[i];
            ar[4 * i + 0] = v.x; ar[4 * i + 1] = v.y; ar[4 * i + 2] = v.z; ar[4 * i + 3] = v.w;
        }
    }

    float4 acc;
    if (HAS_BIAS) acc = *(const float4*)&s_b[c0];
    else { acc.x = 0.f; acc.y = 0.f; acc.z = 0.f; acc.w = 0.f; }
    if (ADD_AGG) {
        float4 v = *(const float4*)(aggadd + (size_t)nn * CO + c0);
        acc.x += v.x; acc.y += v.y; acc.z += v.z; acc.w += v.w;
    }

#pragma unroll
    for (int ci = 0; ci < CI; ci++) {
        if (HAS_REL) {
            float a = ar[ci];
            float4 w = *(const float4*)&s_rel[ci * CO + c0];
            acc.x += a * w.x; acc.y += a * w.y; acc.z += a * w.z; acc.w += a * w.w;
        }
        if (HAS_ROOT) {
            float hv = rr[ci];
            float4 w = *(const float4*)&s_root[ci * CO + c0];
            acc.x += hv * w.x; acc.y += hv * w.y; acc.z += hv * w.z; acc.w += hv * w.w;
        }
    }
    if (valid) *(float4*)(out + (size_t)n * CO + c0) = acc;

    if (STATS) {
        // each thread holds one quad of one node; butterfly across same-quad lanes
        float s0 = valid ? acc.x : 0.f, s1 = valid ? acc.y : 0.f;
        float s2 = valid ? acc.z : 0.f, s3 = valid ? acc.w : 0.f;
        float q0 = s0 * s0, q1 = s1 * s1, q2 = s2 * s2, q3 = s3 * s3;
#pragma unroll
        for (int off = QPR; off < 64; off <<= 1) {
            s0 += __shfl_xor(s0, off, 64); q0 += __shfl_xor(q0, off, 64);
            s1 += __shfl_xor(s1, off, 64); q1 += __shfl_xor(q1, off, 64);
            s2 += __shfl_xor(s2, off, 64); q2 += __shfl_xor(q2, off, 64);
            s3 += __shfl_xor(s3, off, 64); q3 += __shfl_xor(q3, off, 64);
        }
        __shared__ float part[4][2 * CO];
        int lane = threadIdx.x & 63;
        int w = threadIdx.x >> 6;
        if (lane < QPR) {
            int cq = lane * 4;
            part[w][cq + 0] = s0; part[w][CO + cq + 0] = q0;
            part[w][cq + 1] = s1; part[w][CO + cq + 1] = q1;
            part[w][cq + 2] = s2; part[w][CO + cq + 2] = q2;
            part[w][cq + 3] = s3; part[w][CO + cq + 3] = q3;
        }
        __syncthreads();
        if (threadIdx.x < 2 * CO) {
            float v = part[0][threadIdx.x] + part[1][threadIdx.x] + part[2][threadIdx.x] + part[3][threadIdx.x];
            partials[(size_t)blockIdx.x * (2 * CO) + threadIdx.x] = v;  // coalesced, non-atomic
        }
    }
}

// ---------------- partial reduction stage: nb rows -> 64 rows ----------------
__global__ __launch_bounds__(128) void k_sred(const float* __restrict__ partials, float* __restrict__ pred,
                                              int twoCO, int nb) {
    int c = threadIdx.x;
    if (c >= twoCO) return;
    float s = 0.f;
    for (int b = blockIdx.x; b < nb; b += 64) s += partials[(size_t)b * twoCO + c];
    pred[(size_t)blockIdx.x * twoCO + c] = s;
}

// ---------------- stats finalize: reduce 64 rows, produce scale/shift ----------------
__global__ __launch_bounds__(128) void k_sfinal(const float* __restrict__ pred, const float* __restrict__ g,
                                                const float* __restrict__ be, float* __restrict__ stats,
                                                int CO, float invN) {
    __shared__ float red[128];
    int c = threadIdx.x;
    float s = 0.f;
    if (c < 2 * CO) {
        for (int b = 0; b < 64; b++) s += pred[(size_t)b * 2 * CO + c];
    }
    red[c] = s;
    __syncthreads();
    if (c < CO) {
        float mean = red[c] * invN;
        float var = red[CO + c] * invN - mean * mean;
        float sc = g[c] * rsqrtf(var + 1e-5f);
        stats[128 + c] = sc;
        stats[192 + c] = be[c] - mean * sc;
    }
}

// ---------------- gather: one wave per node, predicated uniform-trip loop (no serial tail) ----------------
template <int C>
__global__ __launch_bounds__(256) void k_gather(const float* __restrict__ h, const int* __restrict__ row_start,
                                                const int* __restrict__ csr, float* __restrict__ agg, int N) {
    constexpr int LPR = C / 4;       // lanes per row
    constexpr int EPP = 64 / LPR;    // edges per pass
    int lane = threadIdx.x & 63;
    int wid = blockIdx.x * 4 + (threadIdx.x >> 6);
    if (wid >= N) return;
    int r0 = row_start[wid];
    int deg = row_start[wid + 1] - r0;
    int es = lane / LPR;
    int cq = (lane % LPR) * 4;
    float ax = 0.f, ay = 0.f, az = 0.f, aw = 0.f;
    for (int j0 = 0; j0 < deg; j0 += 4 * EPP) {
        int s[4]; bool p[4];
#pragma unroll
        for (int u = 0; u < 4; u++) {
            int j = j0 + u * EPP + es;
            p[u] = j < deg;
            s[u] = __builtin_nontemporal_load(&csr[r0 + (p[u] ? j : 0)]);  // clamped: all 4 issue together
        }
#pragma unroll
        for (int u = 0; u < 4; u++) {
            float4 v = *(const float4*)(h + (size_t)s[u] * C + cq);
            if (p[u]) { ax += v.x; ay += v.y; az += v.z; aw += v.w; }
        }
    }
#pragma unroll
    for (int off = LPR; off < 64; off <<= 1) {
        ax += __shfl_xor(ax, off, 64);
        ay += __shfl_xor(ay, off, 64);
        az += __shfl_xor(az, off, 64);
        aw += __shfl_xor(aw, off, 64);
    }
    if (lane < LPR) {
        float rec = 1.0f / (float)(deg > 0 ? deg : 1);
        float4 o; o.x = ax * rec; o.y = ay * rec; o.z = az * rec; o.w = aw * rec;
        *(float4*)(agg + (size_t)wid * C + cq) = o;
    }
}

// ---------------- BN apply + ELU, in place ----------------
template <int CO>
__global__ __launch_bounds__(256) void k_bn_elu(float* __restrict__ h, const float* __restrict__ stats, int N) {
    __shared__ float sc[CO], sh[CO];
    if (threadIdx.x < CO) {
        sc[threadIdx.x] = stats[128 + threadIdx.x];
        sh[threadIdx.x] = stats[192 + threadIdx.x];
    }
    __syncthreads();
    int total = N * (CO / 4);
    int i = blockIdx.x * 256 + threadIdx.x;
    if (i >= total) return;
    float4 v = ((float4*)h)[i];
    int cq = (i % (CO / 4)) * 4;
    v.x = v.x * sc[cq + 0] + sh[cq + 0];
    v.y = v.y * sc[cq + 1] + sh[cq + 1];
    v.z = v.z * sc[cq + 2] + sh[cq + 2];
    v.w = v.w * sc[cq + 3] + sh[cq + 3];
    v.x = v.x > 0.f ? v.x : expm1f(v.x);
    v.y = v.y > 0.f ? v.y : expm1f(v.y);
    v.z = v.z > 0.f ? v.z : expm1f(v.z);
    v.w = v.w > 0.f ? v.w : expm1f(v.w);
    ((float4*)h)[i] = v;
}

// ---------------- global mean pool (batch is sorted): run-length segmented reduce ----------------
__global__ __launch_bounds__(256) void k_pool(const float* __restrict__ h, const int* __restrict__ batch,
                                              float* __restrict__ pooled, float* __restrict__ cntg, int N) {
    int lane = threadIdx.x & 63;
    int wid = blockIdx.x * 4 + (threadIdx.x >> 6);
    int n0 = wid * 64;
    if (n0 >= N) return;
    int nmax = N - n0; if (nmax > 64) nmax = 64;
    int cur = batch[n0];
    float acc = 0.f;
    int run = 0;
    for (int k = 0; k < nmax; k++) {
        int g = batch[n0 + k];
        if (g != cur) {
            atomicAdd(&pooled[(size_t)cur * 64 + lane], acc);
            if (lane == 0) atomicAdd(&cntg[cur], (float)run);
            cur = g; acc = 0.f; run = 0;
        }
        acc += h[(size_t)(n0 + k) * 64 + lane];
        run++;
    }
    atomicAdd(&pooled[(size_t)cur * 64 + lane], acc);
    if (lane == 0) atomicAdd(&cntg[cur], (float)run);
}

// ---------------- head ----------------
__global__ __launch_bounds__(256) void k_head(const float* __restrict__ pooled, const float* __restrict__ cntg,
                                              const float* __restrict__ w1, const float* __restrict__ b1,
                                              const float* __restrict__ w2, const float* __restrict__ b2,
                                              float* __restrict__ out) {
    int g = threadIdx.x;  // 256 threads == 256 graphs
    float rec = 1.0f / fmaxf(cntg[g], 1.0f);
    float p[64];
    {
        const float4* pp = (const float4*)(pooled + (size_t)g * 64);
#pragma unroll
        for (int i = 0; i < 16; i++) {
            float4 v = pp[i];
            p[4 * i + 0] = v.x * rec; p[4 * i + 1] = v.y * rec;
            p[4 * i + 2] = v.z * rec; p[4 * i + 3] = v.w * rec;
        }
    }
    float lg[10];
#pragma unroll
    for (int t = 0; t < 10; t++) lg[t] = b2[t];
#pragma unroll 1
    for (int j = 0; j < 64; j++) {
        float a = b1[j];
#pragma unroll
        for (int k = 0; k < 64; k++) a += p[k] * w1[k * 64 + j];  // uniform -> s_load
        a = fmaxf(a, 0.f);
#pragma unroll
        for (int t = 0; t < 10; t++) lg[t] += a * w2[j * 10 + t];
    }
    float m = -1e30f;
#pragma unroll
    for (int t = 0; t < 10; t++) m = fmaxf(m, lg[t]);
    float s = 0.f;
#pragma unroll
    for (int t = 0; t < 10; t++) s += expf(lg[t] - m);
    float lse = m + logf(s);
#pragma unroll
    for (int t = 0; t < 10; t++) out[(size_t)g * 10 + t] = lg[t] - lse;
}

extern "C" void kernel_launch(void* const* d_in, const int* in_sizes, int n_in,
                              void* d_out, int out_size, void* d_ws, size_t ws_size,
                              hipStream_t stream) {
    const float* x = (const float*)d_in[0];
    const int* ei = (const int*)d_in[1];
    const int* batch = (const int*)d_in[2];
    const int N = in_sizes[0] / 64;
    const int E = in_sizes[1] / 2;
    const int* src = ei;
    const int* dst = ei + E;

    const float* w_rel1 = (const float*)d_in[3];
    const float* w_root1 = (const float*)d_in[4];
    const float* b1 = (const float*)d_in[5];
    const float* g1 = (const float*)d_in[6];
    const float* be1 = (const float*)d_in[7];
    const float* w_rel2 = (const float*)d_in[8];
    const float* w_root2 = (const float*)d_in[9];
    const float* b2 = (const float*)d_in[10];
    const float* g2 = (const float*)d_in[11];
    const float* be2 = (const float*)d_in[12];
    const float* w_rel3 = (const float*)d_in[13];
    const float* w_root3 = (const float*)d_in[14];
    const float* b3 = (const float*)d_in[15];
    const float* g3 = (const float*)d_in[16];
    const float* be3 = (const float*)d_in[17];
    const float* w_rel4 = (const float*)d_in[18];
    const float* w_root4 = (const float*)d_in[19];
    const float* b4 = (const float*)d_in[20];
    const float* g4 = (const float*)d_in[21];
    const float* be4 = (const float*)d_in[22];
    const float* w_lin1 = (const float*)d_in[23];
    const float* b_lin1 = (const float*)d_in[24];
    const float* w_lin2 = (const float*)d_in[25];
    const float* b_lin2 = (const float*)d_in[26];

    char* ws = (char*)d_ws;
    size_t off = 0;
    auto alloc = [&](size_t bytes) { size_t o = off; off += (bytes + 255) & ~(size_t)255; return o; };
    int* hmat = (int*)(ws + alloc((size_t)NSORT * NBUCK * 4));
    int* btot = (int*)(ws + alloc((size_t)NBUCK * 4));
    int* bstart = (int*)(ws + alloc((size_t)(NBUCK + 1) * 4));
    unsigned* ebuf = (unsigned*)(ws + alloc((size_t)E * 4));
    int* csr = (int*)(ws + alloc((size_t)E * 4));
    int* row_start = (int*)(ws + alloc((size_t)(N + 1) * 4));
    float* agg = (float*)(ws + alloc((size_t)N * 32 * 4));
    float* y1 = (float*)(ws + alloc((size_t)N * 16 * 4));
    float* bufA = (float*)(ws + alloc((size_t)N * 64 * 4));
    float* bufB = (float*)(ws + alloc((size_t)N * 64 * 4));
    float* stats = (float*)(ws + alloc(4 * 256 * 4));
    const int nb16 = (N * 4 + 255) / 256;
    const int nb32 = (N * 8 + 255) / 256;
    const int nb64 = (N * 16 + 255) / 256;
    float* partials = (float*)(ws + alloc((size_t)nb64 * 128 * 4));
    float* pred = (float*)(ws + alloc((size_t)64 * 128 * 4));
    float* pooled = (float*)(ws + alloc((size_t)(NGRAPHS * 64 + NGRAPHS) * 4));
    float* cntg = pooled + NGRAPHS * 64;

    hipMemsetAsync(pooled, 0, (size_t)(NGRAPHS * 64 + NGRAPHS) * 4, stream);

    const float invN = 1.0f / (float)N;
    const int gbl = (N + 3) / 4;  // gather: 4 waves/block, 1 wave/node

    // ---- CSR build: fully atomic-free (global) counting sort ----
    k_bhist<<<NSORT, 256, 0, stream>>>(dst, hmat, E);
    k_cscan<<<NBUCK / 256, 256, 0, stream>>>(hmat, btot);
    k_bscan<<<1, 1024, 0, stream>>>(btot, bstart);
    k_bscatter<<<NSORT, 256, 0, stream>>>(src, dst, hmat, bstart, ebuf, E);
    k_sort2<<<NBUCK, 256, 0, stream>>>(ebuf, bstart, csr, row_start, N);

    // ---- Layer 1 (64 -> 16): matmul first, aggregate 16 channels ----
    k_lin<64, 16, true, false, false, false, false><<<nb16, 256, 0, stream>>>(
        nullptr, x, w_rel1, nullptr, nullptr, nullptr, y1, nullptr, N);
    k_gather<16><<<gbl, 256, 0, stream>>>(y1, row_start, csr, agg, N);
    k_lin<64, 16, false, true, true, true, true><<<nb16, 256, 0, stream>>>(
        x, nullptr, nullptr, w_root1, b1, agg, bufA, partials, N);
    k_sred<<<64, 128, 0, stream>>>(partials, pred, 32, nb16);
    k_sfinal<<<1, 128, 0, stream>>>(pred, g1, be1, stats + 0, 16, invN);
    k_bn_elu<16><<<(N * 4 + 255) / 256, 256, 0, stream>>>(bufA, stats + 0, N);

    // ---- Layer 2 (16 -> 32) ----
    k_gather<16><<<gbl, 256, 0, stream>>>(bufA, row_start, csr, agg, N);
    k_lin<16, 32, true, true, false, true, true><<<nb32, 256, 0, stream>>>(
        bufA, agg, w_rel2, w_root2, b2, nullptr, bufB, partials, N);
    k_sred<<<64, 128, 0, stream>>>(partials, pred, 64, nb32);
    k_sfinal<<<1, 128, 0, stream>>>(pred, g2, be2, stats + 256, 32, invN);
    k_bn_elu<32><<<(N * 8 + 255) / 256, 256, 0, stream>>>(bufB, stats + 256, N);

    // ---- Layer 3 (32 -> 32) ----
    k_gather<32><<<gbl, 256, 0, stream>>>(bufB, row_start, csr, agg, N);
    k_lin<32, 32, true, true, false, true, true><<<nb32, 256, 0, stream>>>(
        bufB, agg, w_rel3, w_root3, b3, nullptr, bufA, partials, N);
    k_sred<<<64, 128, 0, stream>>>(partials, pred, 64, nb32);
    k_sfinal<<<1, 128, 0, stream>>>(pred, g3, be3, stats + 512, 32, invN);
    k_bn_elu<32><<<(N * 8 + 255) / 256, 256, 0, stream>>>(bufA, stats + 512, N);

    // ---- Layer 4 (32 -> 64) ----
    k_gather<32><<<gbl, 256, 0, stream>>>(bufA, row_start, csr, agg, N);
    k_lin<32, 64, true, true, false, true, true><<<nb64, 256, 0, stream>>>(
        bufA, agg, w_rel4, w_root4, b4, nullptr, bufB, partials, N);
    k_sred<<<64, 128, 0, stream>>>(partials, pred, 128, nb64);
    k_sfinal<<<1, 128, 0, stream>>>(pred, g4, be4, stats + 768, 64, invN);
    k_bn_elu<64><<<(N * 16 + 255) / 256, 256, 0, stream>>>(bufB, stats + 768, N);

    // ---- global mean pool + head ----
    int waves = (N + 63) / 64;
    k_pool<<<(waves + 3) / 4, 256, 0, stream>>>(bufB, batch, pooled, cntg, N);
    k_head<<<1, 256, 0, stream>>>(pooled, cntg, w_lin1, b_lin1, w_lin2, b_lin2, (float*)d_out);
}

// Round 14
// 654.132 us; speedup vs baseline: 1.0741x; 1.0741x over previous
//
#include <hip/hip_runtime.h>
#include <hip/hip_bf16.h>
#include <math.h>

#define NGRAPHS 256
#define BSHIFT 8
#define NBUCK 512    // 256-node buckets; covers N up to 131072
#define NSORT 128    // blocks for bhist/bscatter (256 threads each) — measured sweet spot
#define SBLK 256     // stats blocks (partials)
#define SMASK 0x00FFFFFFu  // low 24 bits = src (N < 2^24)

// ---------------- bucket histogram: per-block LDS hist -> dense matrix (no global atomics) ----------------
__global__ __launch_bounds__(256) void k_bhist(const int* __restrict__ dst, int* __restrict__ hmat, int E) {
    __shared__ int hist[NBUCK];
    for (int i = threadIdx.x; i < NBUCK; i += 256) hist[i] = 0;
    __syncthreads();
    int chunk = (E + NSORT - 1) / NSORT;
    int lo = blockIdx.x * chunk;
    int hi = lo + chunk; if (hi > E) hi = E;
    for (int i = lo + threadIdx.x; i < hi; i += 256) {
        int d = __builtin_nontemporal_load(dst + i);
        atomicAdd(&hist[d >> BSHIFT], 1);
    }
    __syncthreads();
    for (int i = threadIdx.x; i < NBUCK; i += 256)
        hmat[(size_t)blockIdx.x * NBUCK + i] = hist[i];  // coalesced dump
}

// ---------------- column scan: per-bucket exclusive prefix over the NSORT block rows ----------------
__global__ __launch_bounds__(256) void k_cscan(int* __restrict__ hmat, int* __restrict__ btot) {
    int col = blockIdx.x * 256 + threadIdx.x;  // one thread per bucket
    int run = 0;
#pragma unroll 4
    for (int r = 0; r < NSORT; r++) {
        int v = hmat[(size_t)r * NBUCK + col];   // coalesced across threads
        hmat[(size_t)r * NBUCK + col] = run;
        run += v;
    }
    btot[col] = run;
}

// ---------------- bucket scan: one block, 512 threads -> global bucket offsets ----------------
__global__ __launch_bounds__(512) void k_bscan(const int* __restrict__ btot, int* __restrict__ bstart) {
    __shared__ int s[512];
    int tid = threadIdx.x;
    int v = btot[tid];
    s[tid] = v;
    __syncthreads();
    for (int off = 1; off < 512; off <<= 1) {
        int t = (tid >= off) ? s[tid - off] : 0;
        __syncthreads();
        s[tid] += t;
        __syncthreads();
    }
    bstart[tid] = s[tid] - v;  // exclusive
    if (tid == 511) bstart[NBUCK] = s[511];
}

// ---------------- scatter into bucket-ordered ebuf via precomputed LDS cursors ----------------
// pack: word = src | (dst&255)<<24
__global__ __launch_bounds__(256) void k_bscatter(const int* __restrict__ src, const int* __restrict__ dst,
                                                  const int* __restrict__ hmat, const int* __restrict__ bstart,
                                                  unsigned* __restrict__ ebuf, int E) {
    __shared__ int cur[NBUCK];
    for (int i = threadIdx.x; i < NBUCK; i += 256)
        cur[i] = bstart[i] + hmat[(size_t)blockIdx.x * NBUCK + i];
    __syncthreads();
    int chunk = (E + NSORT - 1) / NSORT;
    int lo = blockIdx.x * chunk;
    int hi = lo + chunk; if (hi > E) hi = E;
    for (int i = lo + threadIdx.x; i < hi; i += 256) {
        int d = __builtin_nontemporal_load(dst + i);
        int s = __builtin_nontemporal_load(src + i);
        int p = atomicAdd(&cur[d >> BSHIFT], 1);
        ebuf[p] = (unsigned)s | ((unsigned)(d & 255) << 24);
    }
}

// ---------------- per-bucket LDS counting sort (256 nodes) -> full CSR + row_start ----------------
__global__ __launch_bounds__(256) void k_sort2(const unsigned* __restrict__ ebuf, const int* __restrict__ bstart,
                                               int* __restrict__ csr, int* __restrict__ row_start, int N) {
    __shared__ int hist[256];
    __shared__ int sc[256];
    __shared__ int scur[256];
    int b = blockIdx.x;
    int e0 = bstart[b], e1 = bstart[b + 1];
    hist[threadIdx.x] = 0;
    __syncthreads();
    for (int i = e0 + threadIdx.x; i < e1; i += 256)
        atomicAdd(&hist[__builtin_nontemporal_load(ebuf + i) >> 24], 1);
    __syncthreads();
    // Hillis-Steele inclusive scan over 256 entries
    sc[threadIdx.x] = hist[threadIdx.x];
    __syncthreads();
    for (int off = 1; off < 256; off <<= 1) {
        int t = (threadIdx.x >= off) ? sc[threadIdx.x - off] : 0;
        __syncthreads();
        sc[threadIdx.x] += t;
        __syncthreads();
    }
    {
        int inc = sc[threadIdx.x];
        int ex = inc - hist[threadIdx.x];
        scur[threadIdx.x] = e0 + ex;
        int node = (b << BSHIFT) + threadIdx.x;
        if (node < N) row_start[node] = e0 + ex;
        if (node == N - 1) row_start[N] = e0 + inc;  // == E
    }
    __syncthreads();
    for (int i = e0 + threadIdx.x; i < e1; i += 256) {
        unsigned w = __builtin_nontemporal_load(ebuf + i);
        int p = atomicAdd(&scur[w >> 24], 1);
        csr[p] = (int)(w & SMASK);
    }
}

// ---------------- generic dense layer, one thread per (node, channel-quad) ----------------
template <int CI, int CO, bool HAS_REL, bool HAS_ROOT, bool ADD_AGG, bool HAS_BIAS>
__global__ __launch_bounds__(256) void k_lin(const float* __restrict__ hroot, const float* __restrict__ hrel,
                                             const float* __restrict__ w_rel, const float* __restrict__ w_root,
                                             const float* __restrict__ bias, const float* __restrict__ aggadd,
                                             float* __restrict__ out, int N) {
    constexpr int QPR = CO / 4;
    __shared__ float s_rel[HAS_REL ? CI * CO : 1];
    __shared__ float s_root[HAS_ROOT ? CI * CO : 1];
    __shared__ float s_b[HAS_BIAS ? CO : 4];
    if (HAS_REL)
        for (int i = threadIdx.x; i < CI * CO; i += 256) s_rel[i] = w_rel[i];
    if (HAS_ROOT)
        for (int i = threadIdx.x; i < CI * CO; i += 256) s_root[i] = w_root[i];
    if (HAS_BIAS && threadIdx.x < CO) s_b[threadIdx.x] = bias[threadIdx.x];
    __syncthreads();

    int t = blockIdx.x * 256 + threadIdx.x;
    int n = t / QPR;
    int c0 = (t % QPR) * 4;
    if (n >= N) return;

    float rr[HAS_ROOT ? CI : 1];
    if (HAS_ROOT) {
        const float4* hp = (const float4*)(hroot + (size_t)n * CI);
#pragma unroll
        for (int i = 0; i < CI / 4; i++) {
            float4 v = hp[i];
            rr[4 * i + 0] = v.x; rr[4 * i + 1] = v.y; rr[4 * i + 2] = v.z; rr[4 * i + 3] = v.w;
        }
    }
    float ar[HAS_REL ? CI : 1];
    if (HAS_REL) {
        const float4* mp = (const float4*)(hrel + (size_t)n * CI);
#pragma unroll
        for (int i = 0; i < CI / 4; i++) {
            float4 v = mp[i];
            ar[4 * i + 0] = v.x; ar[4 * i + 1] = v.y; ar[4 * i + 2] = v.z; ar[4 * i + 3] = v.w;
        }
    }

    float4 acc;
    if (HAS_BIAS) acc = *(const float4*)&s_b[c0];
    else { acc.x = 0.f; acc.y = 0.f; acc.z = 0.f; acc.w = 0.f; }
    if (ADD_AGG) {
        float4 v = *(const float4*)(aggadd + (size_t)n * CO + c0);
        acc.x += v.x; acc.y += v.y; acc.z += v.z; acc.w += v.w;
    }

#pragma unroll
    for (int ci = 0; ci < CI; ci++) {
        if (HAS_REL) {
            float a = ar[ci];
            float4 w = *(const float4*)&s_rel[ci * CO + c0];
            acc.x += a * w.x; acc.y += a * w.y; acc.z += a * w.z; acc.w += a * w.w;
        }
        if (HAS_ROOT) {
            float hv = rr[ci];
            float4 w = *(const float4*)&s_root[ci * CO + c0];
            acc.x += hv * w.x; acc.y += hv * w.y; acc.z += hv * w.z; acc.w += hv * w.w;
        }
    }
    *(float4*)(out + (size_t)n * CO + c0) = acc;
}

// ---------------- gather: one wave per node, predicated uniform-trip loop (no serial tail) ----------------
template <int C>
__global__ __launch_bounds__(256) void k_gather(const float* __restrict__ h, const int* __restrict__ row_start,
                                                const int* __restrict__ csr, float* __restrict__ agg, int N) {
    constexpr int LPR = C / 4;       // lanes per row
    constexpr int EPP = 64 / LPR;    // edges per pass
    int lane = threadIdx.x & 63;
    int wid = blockIdx.x * 4 + (threadIdx.x >> 6);
    if (wid >= N) return;
    int r0 = row_start[wid];
    int deg = row_start[wid + 1] - r0;
    int es = lane / LPR;
    int cq = (lane % LPR) * 4;
    float ax = 0.f, ay = 0.f, az = 0.f, aw = 0.f;
    for (int j0 = 0; j0 < deg; j0 += 4 * EPP) {
        int s[4]; bool p[4];
#pragma unroll
        for (int u = 0; u < 4; u++) {
            int j = j0 + u * EPP + es;
            p[u] = j < deg;
            s[u] = __builtin_nontemporal_load(&csr[r0 + (p[u] ? j : 0)]);  // clamped: all 4 issue together
        }
#pragma unroll
        for (int u = 0; u < 4; u++) {
            float4 v = *(const float4*)(h + (size_t)s[u] * C + cq);
            if (p[u]) { ax += v.x; ay += v.y; az += v.z; aw += v.w; }
        }
    }
#pragma unroll
    for (int off = LPR; off < 64; off <<= 1) {
        ax += __shfl_xor(ax, off, 64);
        ay += __shfl_xor(ay, off, 64);
        az += __shfl_xor(az, off, 64);
        aw += __shfl_xor(aw, off, 64);
    }
    if (lane < LPR) {
        float rec = 1.0f / (float)(deg > 0 ? deg : 1);
        float4 o; o.x = ax * rec; o.y = ay * rec; o.z = az * rec; o.w = aw * rec;
        *(float4*)(agg + (size_t)wid * C + cq) = o;
    }
}

// ---------------- BN stats: per-block partials, NO global atomics ----------------
template <int CO>
__global__ __launch_bounds__(256) void k_stats(const float* __restrict__ h, float* __restrict__ partials, int N) {
    constexpr int QPR = CO / 4;
    int total = N * QPR;
    float s0 = 0, s1 = 0, s2 = 0, s3 = 0, q0 = 0, q1 = 0, q2 = 0, q3 = 0;
    int idx = blockIdx.x * 256 + threadIdx.x;
    for (int i = idx; i < total; i += SBLK * 256) {
        float4 v = ((const float4*)h)[i];
        s0 += v.x; q0 += v.x * v.x;
        s1 += v.y; q1 += v.y * v.y;
        s2 += v.z; q2 += v.z * v.z;
        s3 += v.w; q3 += v.w * v.w;
    }
#pragma unroll
    for (int off = QPR; off < 64; off <<= 1) {
        s0 += __shfl_xor(s0, off, 64); q0 += __shfl_xor(q0, off, 64);
        s1 += __shfl_xor(s1, off, 64); q1 += __shfl_xor(q1, off, 64);
        s2 += __shfl_xor(s2, off, 64); q2 += __shfl_xor(q2, off, 64);
        s3 += __shfl_xor(s3, off, 64); q3 += __shfl_xor(q3, off, 64);
    }
    __shared__ float part[4][2 * CO];
    int lane = threadIdx.x & 63;
    int w = threadIdx.x >> 6;
    if (lane < QPR) {
        int cq = lane * 4;
        part[w][cq + 0] = s0; part[w][CO + cq + 0] = q0;
        part[w][cq + 1] = s1; part[w][CO + cq + 1] = q1;
        part[w][cq + 2] = s2; part[w][CO + cq + 2] = q2;
        part[w][cq + 3] = s3; part[w][CO + cq + 3] = q3;
    }
    __syncthreads();
    if (threadIdx.x < 2 * CO) {
        float v = part[0][threadIdx.x] + part[1][threadIdx.x] + part[2][threadIdx.x] + part[3][threadIdx.x];
        partials[blockIdx.x * (2 * CO) + threadIdx.x] = v;  // coalesced, non-atomic
    }
}

// ---------------- stats finalize: reduce partials, produce scale/shift ----------------
__global__ __launch_bounds__(128) void k_sfinal(const float* __restrict__ partials, const float* __restrict__ g,
                                                const float* __restrict__ be, float* __restrict__ stats,
                                                int CO, float invN) {
    __shared__ float red[128];
    int c = threadIdx.x;
    float s = 0.f;
    if (c < 2 * CO) {
        for (int b = 0; b < SBLK; b++) s += partials[b * 2 * CO + c];
    }
    red[c] = s;
    __syncthreads();
    if (c < CO) {
        float mean = red[c] * invN;
        float var = red[CO + c] * invN - mean * mean;
        float sc = g[c] * rsqrtf(var + 1e-5f);
        stats[128 + c] = sc;
        stats[192 + c] = be[c] - mean * sc;
    }
}

// ---------------- BN apply + ELU, in place ----------------
template <int CO>
__global__ __launch_bounds__(256) void k_bn_elu(float* __restrict__ h, const float* __restrict__ stats, int N) {
    __shared__ float sc[CO], sh[CO];
    if (threadIdx.x < CO) {
        sc[threadIdx.x] = stats[128 + threadIdx.x];
        sh[threadIdx.x] = stats[192 + threadIdx.x];
    }
    __syncthreads();
    int total = N * (CO / 4);
    int i = blockIdx.x * 256 + threadIdx.x;
    if (i >= total) return;
    float4 v = ((float4*)h)[i];
    int cq = (i % (CO / 4)) * 4;
    v.x = v.x * sc[cq + 0] + sh[cq + 0];
    v.y = v.y * sc[cq + 1] + sh[cq + 1];
    v.z = v.z * sc[cq + 2] + sh[cq + 2];
    v.w = v.w * sc[cq + 3] + sh[cq + 3];
    v.x = v.x > 0.f ? v.x : expm1f(v.x);
    v.y = v.y > 0.f ? v.y : expm1f(v.y);
    v.z = v.z > 0.f ? v.z : expm1f(v.z);
    v.w = v.w > 0.f ? v.w : expm1f(v.w);
    ((float4*)h)[i] = v;
}

// ---------------- global mean pool (batch is sorted): run-length segmented reduce ----------------
__global__ __launch_bounds__(256) void k_pool(const float* __restrict__ h, const int* __restrict__ batch,
                                              float* __restrict__ pooled, float* __restrict__ cntg, int N) {
    int lane = threadIdx.x & 63;
    int wid = blockIdx.x * 4 + (threadIdx.x >> 6);
    int n0 = wid * 64;
    if (n0 >= N) return;
    int nmax = N - n0; if (nmax > 64) nmax = 64;
    int cur = batch[n0];
    float acc = 0.f;
    int run = 0;
    for (int k = 0; k < nmax; k++) {
        int g = batch[n0 + k];
        if (g != cur) {
            atomicAdd(&pooled[(size_t)cur * 64 + lane], acc);
            if (lane == 0) atomicAdd(&cntg[cur], (float)run);
            cur = g; acc = 0.f; run = 0;
        }
        acc += h[(size_t)(n0 + k) * 64 + lane];
        run++;
    }
    atomicAdd(&pooled[(size_t)cur * 64 + lane], acc);
    if (lane == 0) atomicAdd(&cntg[cur], (float)run);
}

// ---------------- head ----------------
__global__ __launch_bounds__(256) void k_head(const float* __restrict__ pooled, const float* __restrict__ cntg,
                                              const float* __restrict__ w1, const float* __restrict__ b1,
                                              const float* __restrict__ w2, const float* __restrict__ b2,
                                              float* __restrict__ out) {
    int g = threadIdx.x;  // 256 threads == 256 graphs
    float rec = 1.0f / fmaxf(cntg[g], 1.0f);
    float p[64];
    {
        const float4* pp = (const float4*)(pooled + (size_t)g * 64);
#pragma unroll
        for (int i = 0; i < 16; i++) {
            float4 v = pp[i];
            p[4 * i + 0] = v.x * rec; p[4 * i + 1] = v.y * rec;
            p[4 * i + 2] = v.z * rec; p[4 * i + 3] = v.w * rec;
        }
    }
    float lg[10];
#pragma unroll
    for (int t = 0; t < 10; t++) lg[t] = b2[t];
#pragma unroll 1
    for (int j = 0; j < 64; j++) {
        float a = b1[j];
#pragma unroll
        for (int k = 0; k < 64; k++) a += p[k] * w1[k * 64 + j];  // uniform -> s_load
        a = fmaxf(a, 0.f);
#pragma unroll
        for (int t = 0; t < 10; t++) lg[t] += a * w2[j * 10 + t];
    }
    float m = -1e30f;
#pragma unroll
    for (int t = 0; t < 10; t++) m = fmaxf(m, lg[t]);
    float s = 0.f;
#pragma unroll
    for (int t = 0; t < 10; t++) s += expf(lg[t] - m);
    float lse = m + logf(s);
#pragma unroll
    for (int t = 0; t < 10; t++) out[(size_t)g * 10 + t] = lg[t] - lse;
}

extern "C" void kernel_launch(void* const* d_in, const int* in_sizes, int n_in,
                              void* d_out, int out_size, void* d_ws, size_t ws_size,
                              hipStream_t stream) {
    const float* x = (const float*)d_in[0];
    const int* ei = (const int*)d_in[1];
    const int* batch = (const int*)d_in[2];
    const int N = in_sizes[0] / 64;
    const int E = in_sizes[1] / 2;
    const int* src = ei;
    const int* dst = ei + E;

    const float* w_rel1 = (const float*)d_in[3];
    const float* w_root1 = (const float*)d_in[4];
    const float* b1 = (const float*)d_in[5];
    const float* g1 = (const float*)d_in[6];
    const float* be1 = (const float*)d_in[7];
    const float* w_rel2 = (const float*)d_in[8];
    const float* w_root2 = (const float*)d_in[9];
    const float* b2 = (const float*)d_in[10];
    const float* g2 = (const float*)d_in[11];
    const float* be2 = (const float*)d_in[12];
    const float* w_rel3 = (const float*)d_in[13];
    const float* w_root3 = (const float*)d_in[14];
    const float* b3 = (const float*)d_in[15];
    const float* g3 = (const float*)d_in[16];
    const float* be3 = (const float*)d_in[17];
    const float* w_rel4 = (const float*)d_in[18];
    const float* w_root4 = (const float*)d_in[19];
    const float* b4 = (const float*)d_in[20];
    const float* g4 = (const float*)d_in[21];
    const float* be4 = (const float*)d_in[22];
    const float* w_lin1 = (const float*)d_in[23];
    const float* b_lin1 = (const float*)d_in[24];
    const float* w_lin2 = (const float*)d_in[25];
    const float* b_lin2 = (const float*)d_in[26];

    char* ws = (char*)d_ws;
    size_t off = 0;
    auto alloc = [&](size_t bytes) { size_t o = off; off += (bytes + 255) & ~(size_t)255; return o; };
    int* hmat = (int*)(ws + alloc((size_t)NSORT * NBUCK * 4));
    int* btot = (int*)(ws + alloc((size_t)NBUCK * 4));
    int* bstart = (int*)(ws + alloc((size_t)(NBUCK + 1) * 4));
    unsigned* ebuf = (unsigned*)(ws + alloc((size_t)E * 4));
    int* csr = (int*)(ws + alloc((size_t)E * 4));
    int* row_start = (int*)(ws + alloc((size_t)(N + 1) * 4));
    float* agg = (float*)(ws + alloc((size_t)N * 32 * 4));
    float* y1 = (float*)(ws + alloc((size_t)N * 16 * 4));
    float* bufA = (float*)(ws + alloc((size_t)N * 64 * 4));
    float* bufB = (float*)(ws + alloc((size_t)N * 64 * 4));
    float* stats = (float*)(ws + alloc(4 * 256 * 4));
    float* partials = (float*)(ws + alloc((size_t)SBLK * 128 * 4));
    float* pooled = (float*)(ws + alloc((size_t)(NGRAPHS * 64 + NGRAPHS) * 4));
    float* cntg = pooled + NGRAPHS * 64;

    hipMemsetAsync(pooled, 0, (size_t)(NGRAPHS * 64 + NGRAPHS) * 4, stream);

    const float invN = 1.0f / (float)N;
    const int gbl = (N + 3) / 4;  // gather: 4 waves/block, 1 wave/node
    auto lgrid = [&](int qpr) { return (N * qpr + 255) / 256; };

    // ---- CSR build: fully atomic-free (global) counting sort ----
    k_bhist<<<NSORT, 256, 0, stream>>>(dst, hmat, E);
    k_cscan<<<NBUCK / 256, 256, 0, stream>>>(hmat, btot);
    k_bscan<<<1, 512, 0, stream>>>(btot, bstart);
    k_bscatter<<<NSORT, 256, 0, stream>>>(src, dst, hmat, bstart, ebuf, E);
    k_sort2<<<NBUCK, 256, 0, stream>>>(ebuf, bstart, csr, row_start, N);

    // ---- Layer 1 (64 -> 16): matmul first, aggregate 16 channels ----
    k_lin<64, 16, true, false, false, false><<<lgrid(4), 256, 0, stream>>>(
        nullptr, x, w_rel1, nullptr, nullptr, nullptr, y1, N);
    k_gather<16><<<gbl, 256, 0, stream>>>(y1, row_start, csr, agg, N);
    k_lin<64, 16, false, true, true, true><<<lgrid(4), 256, 0, stream>>>(
        x, nullptr, nullptr, w_root1, b1, agg, bufA, N);
    k_stats<16><<<SBLK, 256, 0, stream>>>(bufA, partials, N);
    k_sfinal<<<1, 128, 0, stream>>>(partials, g1, be1, stats + 0, 16, invN);
    k_bn_elu<16><<<(N * 4 + 255) / 256, 256, 0, stream>>>(bufA, stats + 0, N);

    // ---- Layer 2 (16 -> 32) ----
    k_gather<16><<<gbl, 256, 0, stream>>>(bufA, row_start, csr, agg, N);
    k_lin<16, 32, true, true, false, true><<<lgrid(8), 256, 0, stream>>>(
        bufA, agg, w_rel2, w_root2, b2, nullptr, bufB, N);
    k_stats<32><<<SBLK, 256, 0, stream>>>(bufB, partials, N);
    k_sfinal<<<1, 128, 0, stream>>>(partials, g2, be2, stats + 256, 32, invN);
    k_bn_elu<32><<<(N * 8 + 255) / 256, 256, 0, stream>>>(bufB, stats + 256, N);

    // ---- Layer 3 (32 -> 32) ----
    k_gather<32><<<gbl, 256, 0, stream>>>(bufB, row_start, csr, agg, N);
    k_lin<32, 32, true, true, false, true><<<lgrid(8), 256, 0, stream>>>(
        bufB, agg, w_rel3, w_root3, b3, nullptr, bufA, N);
    k_stats<32><<<SBLK, 256, 0, stream>>>(bufA, partials, N);
    k_sfinal<<<1, 128, 0, stream>>>(partials, g3, be3, stats + 512, 32, invN);
    k_bn_elu<32><<<(N * 8 + 255) / 256, 256, 0, stream>>>(bufA, stats + 512, N);

    // ---- Layer 4 (32 -> 64) ----
    k_gather<32><<<gbl, 256, 0, stream>>>(bufA, row_start, csr, agg, N);
    k_lin<32, 64, true, true, false, true><<<lgrid(16), 256, 0, stream>>>(
        bufA, agg, w_rel4, w_root4, b4, nullptr, bufB, N);
    k_stats<64><<<SBLK, 256, 0, stream>>>(bufB, partials, N);
    k_sfinal<<<1, 128, 0, stream>>>(partials, g4, be4, stats + 768, 64, invN);
    k_bn_elu<64><<<(N * 16 + 255) / 256, 256, 0, stream>>>(bufB, stats + 768, N);

    // ---- global mean pool + head ----
    int waves = (N + 63) / 64;
    k_pool<<<(waves + 3) / 4, 256, 0, stream>>>(bufB, batch, pooled, cntg, N);
    k_head<<<1, 256, 0, stream>>>(pooled, cntg, w_lin1, b_lin1, w_lin2, b_lin2, (float*)d_out);
}

// Round 15
// 610.977 us; speedup vs baseline: 1.1499x; 1.0706x over previous
//
#include <hip/hip_runtime.h>
#include <hip/hip_bf16.h>
#include <math.h>

#define NGRAPHS 256
#define BSHIFT 8
#define NBUCK 512    // 256-node buckets; covers N up to 131072
#define NSORT 256    // blocks for bhist/bscatter (256 threads each)
#define SBLK 256     // stats blocks (partials)
#define SMASK 0x00FFFFFFu  // low 24 bits = src (N < 2^24)

__device__ __forceinline__ float bf2f(unsigned short u) {
    return __uint_as_float((unsigned)u << 16);
}
__device__ __forceinline__ unsigned short f2bf(float f) {
    unsigned u = __float_as_uint(f);
    unsigned r = (u + 0x7FFFu + ((u >> 16) & 1u)) >> 16;  // RNE
    return (unsigned short)r;
}

// ---------------- bucket histogram: per-block LDS hist -> dense matrix (no global atomics) ----------------
__global__ __launch_bounds__(256) void k_bhist(const int* __restrict__ dst, int* __restrict__ hmat, int E) {
    __shared__ int hist[NBUCK];
    for (int i = threadIdx.x; i < NBUCK; i += 256) hist[i] = 0;
    __syncthreads();
    int chunk = (E + NSORT - 1) / NSORT;
    int lo = blockIdx.x * chunk;
    int hi = lo + chunk; if (hi > E) hi = E;
    for (int i = lo + threadIdx.x; i < hi; i += 256) {
        int d = __builtin_nontemporal_load(dst + i);
        atomicAdd(&hist[d >> BSHIFT], 1);
    }
    __syncthreads();
    for (int i = threadIdx.x; i < NBUCK; i += 256)
        hmat[(size_t)blockIdx.x * NBUCK + i] = hist[i];  // coalesced dump
}

// ---------------- column scan: per-bucket exclusive prefix over the NSORT block rows ----------------
__global__ __launch_bounds__(256) void k_cscan(int* __restrict__ hmat, int* __restrict__ btot) {
    int col = blockIdx.x * 256 + threadIdx.x;  // one thread per bucket
    int run = 0;
#pragma unroll 4
    for (int r = 0; r < NSORT; r++) {
        int v = hmat[(size_t)r * NBUCK + col];   // coalesced across threads
        hmat[(size_t)r * NBUCK + col] = run;
        run += v;
    }
    btot[col] = run;
}

// ---------------- bucket scan: one block, 512 threads -> global bucket offsets ----------------
__global__ __launch_bounds__(512) void k_bscan(const int* __restrict__ btot, int* __restrict__ bstart) {
    __shared__ int s[512];
    int tid = threadIdx.x;
    int v = btot[tid];
    s[tid] = v;
    __syncthreads();
    for (int off = 1; off < 512; off <<= 1) {
        int t = (tid >= off) ? s[tid - off] : 0;
        __syncthreads();
        s[tid] += t;
        __syncthreads();
    }
    bstart[tid] = s[tid] - v;  // exclusive
    if (tid == 511) bstart[NBUCK] = s[511];
}

// ---------------- scatter into bucket-ordered ebuf via precomputed LDS cursors ----------------
// pack: word = src | (dst&255)<<24
__global__ __launch_bounds__(256) void k_bscatter(const int* __restrict__ src, const int* __restrict__ dst,
                                                  const int* __restrict__ hmat, const int* __restrict__ bstart,
                                                  unsigned* __restrict__ ebuf, int E) {
    __shared__ int cur[NBUCK];
    for (int i = threadIdx.x; i < NBUCK; i += 256)
        cur[i] = bstart[i] + hmat[(size_t)blockIdx.x * NBUCK + i];
    __syncthreads();
    int chunk = (E + NSORT - 1) / NSORT;
    int lo = blockIdx.x * chunk;
    int hi = lo + chunk; if (hi > E) hi = E;
    for (int i = lo + threadIdx.x; i < hi; i += 256) {
        int d = __builtin_nontemporal_load(dst + i);
        int s = __builtin_nontemporal_load(src + i);
        int p = atomicAdd(&cur[d >> BSHIFT], 1);
        ebuf[p] = (unsigned)s | ((unsigned)(d & 255) << 24);
    }
}

// ---------------- per-bucket LDS counting sort (256 nodes) -> full CSR + row_start ----------------
__global__ __launch_bounds__(256) void k_sort2(const unsigned* __restrict__ ebuf, const int* __restrict__ bstart,
                                               int* __restrict__ csr, int* __restrict__ row_start, int N) {
    __shared__ int hist[256];
    __shared__ int sc[256];
    __shared__ int scur[256];
    int b = blockIdx.x;
    int e0 = bstart[b], e1 = bstart[b + 1];
    hist[threadIdx.x] = 0;
    __syncthreads();
    for (int i = e0 + threadIdx.x; i < e1; i += 256)
        atomicAdd(&hist[__builtin_nontemporal_load(ebuf + i) >> 24], 1);
    __syncthreads();
    // Hillis-Steele inclusive scan over 256 entries
    sc[threadIdx.x] = hist[threadIdx.x];
    __syncthreads();
    for (int off = 1; off < 256; off <<= 1) {
        int t = (threadIdx.x >= off) ? sc[threadIdx.x - off] : 0;
        __syncthreads();
        sc[threadIdx.x] += t;
        __syncthreads();
    }
    {
        int inc = sc[threadIdx.x];
        int ex = inc - hist[threadIdx.x];
        scur[threadIdx.x] = e0 + ex;
        int node = (b << BSHIFT) + threadIdx.x;
        if (node < N) row_start[node] = e0 + ex;
        if (node == N - 1) row_start[N] = e0 + inc;  // == E
    }
    __syncthreads();
    for (int i = e0 + threadIdx.x; i < e1; i += 256) {
        unsigned w = __builtin_nontemporal_load(ebuf + i);
        int p = atomicAdd(&scur[w >> 24], 1);
        csr[p] = (int)(w & SMASK);
    }
}

// ---------------- generic dense layer, one thread per (node, channel-quad) ----------------
// IN_BF16: hroot is bf16.  OUT_BF16: write bf16 to outb instead of fp32 to out.
template <int CI, int CO, bool HAS_REL, bool HAS_ROOT, bool ADD_AGG, bool HAS_BIAS, bool IN_BF16, bool OUT_BF16>
__global__ __launch_bounds__(256) void k_lin(const void* __restrict__ hroot_v, const float* __restrict__ hrel,
                                             const float* __restrict__ w_rel, const float* __restrict__ w_root,
                                             const float* __restrict__ bias, const float* __restrict__ aggadd,
                                             float* __restrict__ out, unsigned short* __restrict__ outb, int N) {
    constexpr int QPR = CO / 4;
    __shared__ float s_rel[HAS_REL ? CI * CO : 1];
    __shared__ float s_root[HAS_ROOT ? CI * CO : 1];
    __shared__ float s_b[HAS_BIAS ? CO : 4];
    if (HAS_REL)
        for (int i = threadIdx.x; i < CI * CO; i += 256) s_rel[i] = w_rel[i];
    if (HAS_ROOT)
        for (int i = threadIdx.x; i < CI * CO; i += 256) s_root[i] = w_root[i];
    if (HAS_BIAS && threadIdx.x < CO) s_b[threadIdx.x] = bias[threadIdx.x];
    __syncthreads();

    int t = blockIdx.x * 256 + threadIdx.x;
    int n = t / QPR;
    int c0 = (t % QPR) * 4;
    if (n >= N) return;

    float rr[HAS_ROOT ? CI : 1];
    if (HAS_ROOT) {
        if (IN_BF16) {
            const ushort4* hp = (const ushort4*)((const unsigned short*)hroot_v + (size_t)n * CI);
#pragma unroll
            for (int i = 0; i < CI / 4; i++) {
                ushort4 v = hp[i];
                rr[4 * i + 0] = bf2f(v.x); rr[4 * i + 1] = bf2f(v.y);
                rr[4 * i + 2] = bf2f(v.z); rr[4 * i + 3] = bf2f(v.w);
            }
        } else {
            const float4* hp = (const float4*)((const float*)hroot_v + (size_t)n * CI);
#pragma unroll
            for (int i = 0; i < CI / 4; i++) {
                float4 v = hp[i];
                rr[4 * i + 0] = v.x; rr[4 * i + 1] = v.y; rr[4 * i + 2] = v.z; rr[4 * i + 3] = v.w;
            }
        }
    }
    float ar[HAS_REL ? CI : 1];
    if (HAS_REL) {
        const float4* mp = (const float4*)(hrel + (size_t)n * CI);
#pragma unroll
        for (int i = 0; i < CI / 4; i++) {
            float4 v = mp[i];
            ar[4 * i + 0] = v.x; ar[4 * i + 1] = v.y; ar[4 * i + 2] = v.z; ar[4 * i + 3] = v.w;
        }
    }

    float4 acc;
    if (HAS_BIAS) acc = *(const float4*)&s_b[c0];
    else { acc.x = 0.f; acc.y = 0.f; acc.z = 0.f; acc.w = 0.f; }
    if (ADD_AGG) {
        float4 v = *(const float4*)(aggadd + (size_t)n * CO + c0);
        acc.x += v.x; acc.y += v.y; acc.z += v.z; acc.w += v.w;
    }

#pragma unroll
    for (int ci = 0; ci < CI; ci++) {
        if (HAS_REL) {
            float a = ar[ci];
            float4 w = *(const float4*)&s_rel[ci * CO + c0];
            acc.x += a * w.x; acc.y += a * w.y; acc.z += a * w.z; acc.w += a * w.w;
        }
        if (HAS_ROOT) {
            float hv = rr[ci];
            float4 w = *(const float4*)&s_root[ci * CO + c0];
            acc.x += hv * w.x; acc.y += hv * w.y; acc.z += hv * w.z; acc.w += hv * w.w;
        }
    }
    if (OUT_BF16) {
        ushort4 o;
        o.x = f2bf(acc.x); o.y = f2bf(acc.y); o.z = f2bf(acc.z); o.w = f2bf(acc.w);
        *(ushort4*)(outb + (size_t)n * CO + c0) = o;
    } else {
        *(float4*)(out + (size_t)n * CO + c0) = acc;
    }
}

// ---------------- gather (bf16 input): one wave per node, predicated uniform-trip loop ----------------
template <int C>
__global__ __launch_bounds__(256) void k_gather(const unsigned short* __restrict__ h,
                                                const int* __restrict__ row_start,
                                                const int* __restrict__ csr, float* __restrict__ agg, int N) {
    constexpr int LPR = C / 4;       // lanes per row
    constexpr int EPP = 64 / LPR;    // edges per pass
    int lane = threadIdx.x & 63;
    int wid = blockIdx.x * 4 + (threadIdx.x >> 6);
    if (wid >= N) return;
    int r0 = row_start[wid];
    int deg = row_start[wid + 1] - r0;
    int es = lane / LPR;
    int cq = (lane % LPR) * 4;
    float ax = 0.f, ay = 0.f, az = 0.f, aw = 0.f;
    for (int j0 = 0; j0 < deg; j0 += 4 * EPP) {
        int s[4]; bool p[4];
#pragma unroll
        for (int u = 0; u < 4; u++) {
            int j = j0 + u * EPP + es;
            p[u] = j < deg;
            s[u] = __builtin_nontemporal_load(&csr[r0 + (p[u] ? j : 0)]);  // clamped: all 4 issue together
        }
#pragma unroll
        for (int u = 0; u < 4; u++) {
            ushort4 v = *(const ushort4*)(h + (size_t)s[u] * C + cq);
            if (p[u]) {
                ax += bf2f(v.x); ay += bf2f(v.y); az += bf2f(v.z); aw += bf2f(v.w);
            }
        }
    }
#pragma unroll
    for (int off = LPR; off < 64; off <<= 1) {
        ax += __shfl_xor(ax, off, 64);
        ay += __shfl_xor(ay, off, 64);
        az += __shfl_xor(az, off, 64);
        aw += __shfl_xor(aw, off, 64);
    }
    if (lane < LPR) {
        float rec = 1.0f / (float)(deg > 0 ? deg : 1);
        float4 o; o.x = ax * rec; o.y = ay * rec; o.z = az * rec; o.w = aw * rec;
        *(float4*)(agg + (size_t)wid * C + cq) = o;
    }
}

// ---------------- BN stats: per-block partials, NO global atomics (reads fp32 pre-activation) ----------------
template <int CO>
__global__ __launch_bounds__(256) void k_stats(const float* __restrict__ h, float* __restrict__ partials, int N) {
    constexpr int QPR = CO / 4;
    int total = N * QPR;
    float s0 = 0, s1 = 0, s2 = 0, s3 = 0, q0 = 0, q1 = 0, q2 = 0, q3 = 0;
    int idx = blockIdx.x * 256 + threadIdx.x;
    for (int i = idx; i < total; i += SBLK * 256) {
        float4 v = ((const float4*)h)[i];
        s0 += v.x; q0 += v.x * v.x;
        s1 += v.y; q1 += v.y * v.y;
        s2 += v.z; q2 += v.z * v.z;
        s3 += v.w; q3 += v.w * v.w;
    }
#pragma unroll
    for (int off = QPR; off < 64; off <<= 1) {
        s0 += __shfl_xor(s0, off, 64); q0 += __shfl_xor(q0, off, 64);
        s1 += __shfl_xor(s1, off, 64); q1 += __shfl_xor(q1, off, 64);
        s2 += __shfl_xor(s2, off, 64); q2 += __shfl_xor(q2, off, 64);
        s3 += __shfl_xor(s3, off, 64); q3 += __shfl_xor(q3, off, 64);
    }
    __shared__ float part[4][2 * CO];
    int lane = threadIdx.x & 63;
    int w = threadIdx.x >> 6;
    if (lane < QPR) {
        int cq = lane * 4;
        part[w][cq + 0] = s0; part[w][CO + cq + 0] = q0;
        part[w][cq + 1] = s1; part[w][CO + cq + 1] = q1;
        part[w][cq + 2] = s2; part[w][CO + cq + 2] = q2;
        part[w][cq + 3] = s3; part[w][CO + cq + 3] = q3;
    }
    __syncthreads();
    if (threadIdx.x < 2 * CO) {
        float v = part[0][threadIdx.x] + part[1][threadIdx.x] + part[2][threadIdx.x] + part[3][threadIdx.x];
        partials[blockIdx.x * (2 * CO) + threadIdx.x] = v;  // coalesced, non-atomic
    }
}

// ---------------- stats finalize: reduce partials, produce scale/shift ----------------
__global__ __launch_bounds__(128) void k_sfinal(const float* __restrict__ partials, const float* __restrict__ g,
                                                const float* __restrict__ be, float* __restrict__ stats,
                                                int CO, float invN) {
    __shared__ float red[128];
    int c = threadIdx.x;
    float s = 0.f;
    if (c < 2 * CO) {
        for (int b = 0; b < SBLK; b++) s += partials[b * 2 * CO + c];
    }
    red[c] = s;
    __syncthreads();
    if (c < CO) {
        float mean = red[c] * invN;
        float var = red[CO + c] * invN - mean * mean;
        float sc = g[c] * rsqrtf(var + 1e-5f);
        stats[128 + c] = sc;
        stats[192 + c] = be[c] - mean * sc;
    }
}

// ---------------- BN apply + ELU: read fp32, write bf16 activated features ----------------
template <int CO>
__global__ __launch_bounds__(256) void k_bn_elu(const float* __restrict__ h, const float* __restrict__ stats,
                                                unsigned short* __restrict__ hb, int N) {
    __shared__ float sc[CO], sh[CO];
    if (threadIdx.x < CO) {
        sc[threadIdx.x] = stats[128 + threadIdx.x];
        sh[threadIdx.x] = stats[192 + threadIdx.x];
    }
    __syncthreads();
    int total = N * (CO / 4);
    int i = blockIdx.x * 256 + threadIdx.x;
    if (i >= total) return;
    float4 v = ((const float4*)h)[i];
    int cq = (i % (CO / 4)) * 4;
    v.x = v.x * sc[cq + 0] + sh[cq + 0];
    v.y = v.y * sc[cq + 1] + sh[cq + 1];
    v.z = v.z * sc[cq + 2] + sh[cq + 2];
    v.w = v.w * sc[cq + 3] + sh[cq + 3];
    v.x = v.x > 0.f ? v.x : expm1f(v.x);
    v.y = v.y > 0.f ? v.y : expm1f(v.y);
    v.z = v.z > 0.f ? v.z : expm1f(v.z);
    v.w = v.w > 0.f ? v.w : expm1f(v.w);
    ushort4 o;
    o.x = f2bf(v.x); o.y = f2bf(v.y); o.z = f2bf(v.z); o.w = f2bf(v.w);
    ((ushort4*)hb)[i] = o;
}

// ---------------- global mean pool (batch is sorted, bf16 input): run-length segmented reduce ----------------
__global__ __launch_bounds__(256) void k_pool(const unsigned short* __restrict__ hb, const int* __restrict__ batch,
                                              float* __restrict__ pooled, float* __restrict__ cntg, int N) {
    int lane = threadIdx.x & 63;
    int wid = blockIdx.x * 4 + (threadIdx.x >> 6);
    int n0 = wid * 64;
    if (n0 >= N) return;
    int nmax = N - n0; if (nmax > 64) nmax = 64;
    int cur = batch[n0];
    float acc = 0.f;
    int run = 0;
    for (int k = 0; k < nmax; k++) {
        int g = batch[n0 + k];
        if (g != cur) {
            atomicAdd(&pooled[(size_t)cur * 64 + lane], acc);
            if (lane == 0) atomicAdd(&cntg[cur], (float)run);
            cur = g; acc = 0.f; run = 0;
        }
        acc += bf2f(hb[(size_t)(n0 + k) * 64 + lane]);
        run++;
    }
    atomicAdd(&pooled[(size_t)cur * 64 + lane], acc);
    if (lane == 0) atomicAdd(&cntg[cur], (float)run);
}

// ---------------- head ----------------
__global__ __launch_bounds__(256) void k_head(const float* __restrict__ pooled, const float* __restrict__ cntg,
                                              const float* __restrict__ w1, const float* __restrict__ b1,
                                              const float* __restrict__ w2, const float* __restrict__ b2,
                                              float* __restrict__ out) {
    int g = threadIdx.x;  // 256 threads == 256 graphs
    float rec = 1.0f / fmaxf(cntg[g], 1.0f);
    float p[64];
    {
        const float4* pp = (const float4*)(pooled + (size_t)g * 64);
#pragma unroll
        for (int i = 0; i < 16; i++) {
            float4 v = pp[i];
            p[4 * i + 0] = v.x * rec; p[4 * i + 1] = v.y * rec;
            p[4 * i + 2] = v.z * rec; p[4 * i + 3] = v.w * rec;
        }
    }
    float lg[10];
#pragma unroll
    for (int t = 0; t < 10; t++) lg[t] = b2[t];
#pragma unroll 1
    for (int j = 0; j < 64; j++) {
        float a = b1[j];
#pragma unroll
        for (int k = 0; k < 64; k++) a += p[k] * w1[k * 64 + j];  // uniform -> s_load
        a = fmaxf(a, 0.f);
#pragma unroll
        for (int t = 0; t < 10; t++) lg[t] += a * w2[j * 10 + t];
    }
    float m = -1e30f;
#pragma unroll
    for (int t = 0; t < 10; t++) m = fmaxf(m, lg[t]);
    float s = 0.f;
#pragma unroll
    for (int t = 0; t < 10; t++) s += expf(lg[t] - m);
    float lse = m + logf(s);
#pragma unroll
    for (int t = 0; t < 10; t++) out[(size_t)g * 10 + t] = lg[t] - lse;
}

extern "C" void kernel_launch(void* const* d_in, const int* in_sizes, int n_in,
                              void* d_out, int out_size, void* d_ws, size_t ws_size,
                              hipStream_t stream) {
    const float* x = (const float*)d_in[0];
    const int* ei = (const int*)d_in[1];
    const int* batch = (const int*)d_in[2];
    const int N = in_sizes[0] / 64;
    const int E = in_sizes[1] / 2;
    const int* src = ei;
    const int* dst = ei + E;

    const float* w_rel1 = (const float*)d_in[3];
    const float* w_root1 = (const float*)d_in[4];
    const float* b1 = (const float*)d_in[5];
    const float* g1 = (const float*)d_in[6];
    const float* be1 = (const float*)d_in[7];
    const float* w_rel2 = (const float*)d_in[8];
    const float* w_root2 = (const float*)d_in[9];
    const float* b2 = (const float*)d_in[10];
    const float* g2 = (const float*)d_in[11];
    const float* be2 = (const float*)d_in[12];
    const float* w_rel3 = (const float*)d_in[13];
    const float* w_root3 = (const float*)d_in[14];
    const float* b3 = (const float*)d_in[15];
    const float* g3 = (const float*)d_in[16];
    const float* be3 = (const float*)d_in[17];
    const float* w_rel4 = (const float*)d_in[18];
    const float* w_root4 = (const float*)d_in[19];
    const float* b4 = (const float*)d_in[20];
    const float* g4 = (const float*)d_in[21];
    const float* be4 = (const float*)d_in[22];
    const float* w_lin1 = (const float*)d_in[23];
    const float* b_lin1 = (const float*)d_in[24];
    const float* w_lin2 = (const float*)d_in[25];
    const float* b_lin2 = (const float*)d_in[26];

    char* ws = (char*)d_ws;
    size_t off = 0;
    auto alloc = [&](size_t bytes) { size_t o = off; off += (bytes + 255) & ~(size_t)255; return o; };
    int* hmat = (int*)(ws + alloc((size_t)NSORT * NBUCK * 4));
    int* btot = (int*)(ws + alloc((size_t)NBUCK * 4));
    int* bstart = (int*)(ws + alloc((size_t)(NBUCK + 1) * 4));
    unsigned* ebuf = (unsigned*)(ws + alloc((size_t)E * 4));
    int* csr = (int*)(ws + alloc((size_t)E * 4));
    int* row_start = (int*)(ws + alloc((size_t)(N + 1) * 4));
    float* agg = (float*)(ws + alloc((size_t)N * 32 * 4));
    unsigned short* y1b = (unsigned short*)(ws + alloc((size_t)N * 16 * 2));
    unsigned short* hb = (unsigned short*)(ws + alloc((size_t)N * 64 * 2));
    float* bufA = (float*)(ws + alloc((size_t)N * 64 * 4));
    float* stats = (float*)(ws + alloc(4 * 256 * 4));
    float* partials = (float*)(ws + alloc((size_t)SBLK * 128 * 4));
    float* pooled = (float*)(ws + alloc((size_t)(NGRAPHS * 64 + NGRAPHS) * 4));
    float* cntg = pooled + NGRAPHS * 64;

    hipMemsetAsync(pooled, 0, (size_t)(NGRAPHS * 64 + NGRAPHS) * 4, stream);

    const float invN = 1.0f / (float)N;
    const int gbl = (N + 3) / 4;  // gather: 4 waves/block, 1 wave/node
    auto lgrid = [&](int qpr) { return (N * qpr + 255) / 256; };

    // ---- CSR build: fully atomic-free (global) counting sort ----
    k_bhist<<<NSORT, 256, 0, stream>>>(dst, hmat, E);
    k_cscan<<<NBUCK / 256, 256, 0, stream>>>(hmat, btot);
    k_bscan<<<1, 512, 0, stream>>>(btot, bstart);
    k_bscatter<<<NSORT, 256, 0, stream>>>(src, dst, hmat, bstart, ebuf, E);
    k_sort2<<<NBUCK, 256, 0, stream>>>(ebuf, bstart, csr, row_start, N);

    // ---- Layer 1 (64 -> 16): matmul first (bf16 out), aggregate 16 channels ----
    k_lin<64, 16, true, false, false, false, false, true><<<lgrid(4), 256, 0, stream>>>(
        nullptr, x, w_rel1, nullptr, nullptr, nullptr, nullptr, y1b, N);
    k_gather<16><<<gbl, 256, 0, stream>>>(y1b, row_start, csr, agg, N);
    k_lin<64, 16, false, true, true, true, false, false><<<lgrid(4), 256, 0, stream>>>(
        x, nullptr, nullptr, w_root1, b1, agg, bufA, nullptr, N);
    k_stats<16><<<SBLK, 256, 0, stream>>>(bufA, partials, N);
    k_sfinal<<<1, 128, 0, stream>>>(partials, g1, be1, stats + 0, 16, invN);
    k_bn_elu<16><<<(N * 4 + 255) / 256, 256, 0, stream>>>(bufA, stats + 0, hb, N);

    // ---- Layer 2 (16 -> 32) ----
    k_gather<16><<<gbl, 256, 0, stream>>>(hb, row_start, csr, agg, N);
    k_lin<16, 32, true, true, false, true, true, false><<<lgrid(8), 256, 0, stream>>>(
        hb, agg, w_rel2, w_root2, b2, nullptr, bufA, nullptr, N);
    k_stats<32><<<SBLK, 256, 0, stream>>>(bufA, partials, N);
    k_sfinal<<<1, 128, 0, stream>>>(partials, g2, be2, stats + 256, 32, invN);
    k_bn_elu<32><<<(N * 8 + 255) / 256, 256, 0, stream>>>(bufA, stats + 256, hb, N);

    // ---- Layer 3 (32 -> 32) ----
    k_gather<32><<<gbl, 256, 0, stream>>>(hb, row_start, csr, agg, N);
    k_lin<32, 32, true, true, false, true, true, false><<<lgrid(8), 256, 0, stream>>>(
        hb, agg, w_rel3, w_root3, b3, nullptr, bufA, nullptr, N);
    k_stats<32><<<SBLK, 256, 0, stream>>>(bufA, partials, N);
    k_sfinal<<<1, 128, 0, stream>>>(partials, g3, be3, stats + 512, 32, invN);
    k_bn_elu<32><<<(N * 8 + 255) / 256, 256, 0, stream>>>(bufA, stats + 512, hb, N);

    // ---- Layer 4 (32 -> 64) ----
    k_gather<32><<<gbl, 256, 0, stream>>>(hb, row_start, csr, agg, N);
    k_lin<32, 64, true, true, false, true, true, false><<<lgrid(16), 256, 0, stream>>>(
        hb, agg, w_rel4, w_root4, b4, nullptr, bufA, nullptr, N);
    k_stats<64><<<SBLK, 256, 0, stream>>>(bufA, partials, N);
    k_sfinal<<<1, 128, 0, stream>>>(partials, g4, be4, stats + 768, 64, invN);
    k_bn_elu<64><<<(N * 16 + 255) / 256, 256, 0, stream>>>(bufA, stats + 768, hb, N);

    // ---- global mean pool + head ----
    int waves = (N + 63) / 64;
    k_pool<<<(waves + 3) / 4, 256, 0, stream>>>(hb, batch, pooled, cntg, N);
    k_head<<<1, 256, 0, stream>>>(pooled, cntg, w_lin1, b_lin1, w_lin2, b_lin2, (float*)d_out);
}